// Round 1
// baseline (1905.111 us; speedup 1.0000x reference)
//
#include <hip/hip_runtime.h>
#include <hip/hip_bf16.h>
#include <math.h>

// Problem constants
// x: [4, 2048, 1024] fp32; Wq/Wk/Wv: [1024,1024]; Wo: [1024,1024]; bo: [1024]
// out: [4, 2048, 1024] fp32
// M = B*S = 8192, D = 1024, H = 16, Dh = 64
static constexpr int Mtot = 8192;
static constexpr int Dmod = 1024;
static constexpr int SEQ  = 2048;
static constexpr int NH   = 16;
static constexpr int DH   = 64;

// ---------------------------------------------------------------------------
// SGEMM: C[M,N] = A[M,K] @ W[K,N] (+ bias). BM=BN=128, BK=8, 256 thr, 8x8/thr
// ---------------------------------------------------------------------------
template<bool BIAS>
__global__ __launch_bounds__(256)
void sgemm128(const float* __restrict__ A, const float* __restrict__ W,
              const float* __restrict__ bias, float* __restrict__ C,
              int M, int N, int K) {
    constexpr int BM = 128, BN = 128, BK = 8;
    __shared__ float As[BK][BM];   // A tile, transposed
    __shared__ float Bs[BK][BN];

    const int t  = threadIdx.x;
    const int m0 = blockIdx.y * BM;
    const int n0 = blockIdx.x * BN;
    const int tq = t >> 4;         // 0..15 (row group)
    const int tk = t & 15;         // 0..15 (col group)

    // A load: thread t -> row m0 + t/2, k offset (t&1)*4 (one float4)
    const int arow = t >> 1;
    const int acol = (t & 1) * 4;
    // B load: thread t -> k row t/32, col offset (t&31)*4 (one float4)
    const int brow = t >> 5;
    const int bcol = (t & 31) * 4;

    float acc[8][8] = {};

    for (int k0 = 0; k0 < K; k0 += BK) {
        float4 av = *(const float4*)&A[(size_t)(m0 + arow) * K + k0 + acol];
        float4 bv = *(const float4*)&W[(size_t)(k0 + brow) * N + n0 + bcol];
        __syncthreads();           // protect previous iteration's reads
        As[acol + 0][arow] = av.x;
        As[acol + 1][arow] = av.y;
        As[acol + 2][arow] = av.z;
        As[acol + 3][arow] = av.w;
        *(float4*)&Bs[brow][bcol] = bv;
        __syncthreads();
#pragma unroll
        for (int kk = 0; kk < BK; ++kk) {
            float a[8], b[8];
            *(float4*)&a[0] = *(const float4*)&As[kk][tq * 8];
            *(float4*)&a[4] = *(const float4*)&As[kk][tq * 8 + 4];
            *(float4*)&b[0] = *(const float4*)&Bs[kk][tk * 8];
            *(float4*)&b[4] = *(const float4*)&Bs[kk][tk * 8 + 4];
#pragma unroll
            for (int i = 0; i < 8; ++i)
#pragma unroll
                for (int j = 0; j < 8; ++j)
                    acc[i][j] = fmaf(a[i], b[j], acc[i][j]);
        }
    }

#pragma unroll
    for (int i = 0; i < 8; ++i) {
        const int row = m0 + tq * 8 + i;
        float* dst = &C[(size_t)row * N + n0 + tk * 8];
        float4 v0 = make_float4(acc[i][0], acc[i][1], acc[i][2], acc[i][3]);
        float4 v1 = make_float4(acc[i][4], acc[i][5], acc[i][6], acc[i][7]);
        if constexpr (BIAS) {
            const float* bb = &bias[n0 + tk * 8];
            v0.x += bb[0]; v0.y += bb[1]; v0.z += bb[2]; v0.w += bb[3];
            v1.x += bb[4]; v1.y += bb[5]; v1.z += bb[6]; v1.w += bb[7];
        }
        *(float4*)&dst[0] = v0;
        *(float4*)&dst[4] = v1;
    }
}

// ---------------------------------------------------------------------------
// Fused causal attention, flash-style. One block = one (b,h) x 64-query tile.
// Q/K/V in [B*S, H*Dh] row-major (head h occupies cols h*64..h*64+63).
// 256 threads: tq = t>>4 owns q rows tq*4+i; tk = t&15.
//   Scores phase: thread owns k cols {tk + 16*jj}.
//   PV phase:     thread owns d cols {tk*4 + j}.
// ---------------------------------------------------------------------------
__global__ __launch_bounds__(256)
void attn_fused(const float* __restrict__ Q, const float* __restrict__ K,
                const float* __restrict__ V, float* __restrict__ O) {
    constexpr int LD = 68;           // LDS row stride (floats): 16B-aligned, spreads banks
    __shared__ float Qs[64][LD];
    __shared__ float Ks[64][LD];
    __shared__ float Vs[64][LD];
    __shared__ float Ps[64][LD];     // P stored transposed: Ps[k_local][q_local]

    const int qt = blockIdx.x;       // 0..31
    const int bh = blockIdx.y;       // 0..63
    const int b  = bh >> 4;
    const int h  = bh & 15;
    const int t  = threadIdx.x;
    const int tq = t >> 4;
    const int tk = t & 15;

    const size_t base = (size_t)b * SEQ * Dmod + (size_t)h * DH;
    const int q0 = qt * 64;

    // Load+scale Q tile: 64x64 floats, 4 float4 per thread, coalesced.
#pragma unroll
    for (int i = 0; i < 4; ++i) {
        const int idx = t + i * 256;
        const int r = idx >> 4, c = (idx & 15) * 4;
        float4 v = *(const float4*)&Q[base + (size_t)(q0 + r) * Dmod + c];
        v.x *= 0.125f; v.y *= 0.125f; v.z *= 0.125f; v.w *= 0.125f;
        *(float4*)&Qs[r][c] = v;
    }

    float m_i[4], l_i[4], acc[4][4];
#pragma unroll
    for (int i = 0; i < 4; ++i) {
        m_i[i] = -INFINITY; l_i[i] = 0.f;
#pragma unroll
        for (int j = 0; j < 4; ++j) acc[i][j] = 0.f;
    }

    for (int jt = 0; jt <= qt; ++jt) {
        const int k0 = jt * 64;
        __syncthreads();   // previous tile's reads of Ks/Vs done (also covers Qs on iter 0)
#pragma unroll
        for (int i = 0; i < 4; ++i) {
            const int idx = t + i * 256;
            const int r = idx >> 4, c = (idx & 15) * 4;
            *(float4*)&Ks[r][c] = *(const float4*)&K[base + (size_t)(k0 + r) * Dmod + c];
            *(float4*)&Vs[r][c] = *(const float4*)&V[base + (size_t)(k0 + r) * Dmod + c];
        }
        __syncthreads();

        // ---- scores: sc[i][jj] = q(tq*4+i) . k(tk+16*jj), both pre-scaled by 1/8 on Q
        float sc[4][4] = {};
#pragma unroll
        for (int kk = 0; kk < 64; kk += 4) {
            float4 qv[4], kv[4];
#pragma unroll
            for (int i = 0; i < 4; ++i)  qv[i] = *(const float4*)&Qs[tq * 4 + i][kk];
#pragma unroll
            for (int jj = 0; jj < 4; ++jj) kv[jj] = *(const float4*)&Ks[tk + 16 * jj][kk];
#pragma unroll
            for (int i = 0; i < 4; ++i)
#pragma unroll
                for (int jj = 0; jj < 4; ++jj) {
                    sc[i][jj] = fmaf(qv[i].x, kv[jj].x, sc[i][jj]);
                    sc[i][jj] = fmaf(qv[i].y, kv[jj].y, sc[i][jj]);
                    sc[i][jj] = fmaf(qv[i].z, kv[jj].z, sc[i][jj]);
                    sc[i][jj] = fmaf(qv[i].w, kv[jj].w, sc[i][jj]);
                }
        }

        // causal mask (only the diagonal tile needs it: k0 == q0)
        if (jt == qt) {
#pragma unroll
            for (int i = 0; i < 4; ++i) {
                const int qg = tq * 4 + i;
#pragma unroll
                for (int jj = 0; jj < 4; ++jj) {
                    const int kg = tk + 16 * jj;
                    if (kg > qg) sc[i][jj] = -INFINITY;
                }
            }
        }

        // ---- online softmax update
        float rmax[4], rsum[4], mnew[4], scale[4];
#pragma unroll
        for (int i = 0; i < 4; ++i) {
            float mx = fmaxf(fmaxf(sc[i][0], sc[i][1]), fmaxf(sc[i][2], sc[i][3]));
#pragma unroll
            for (int off = 1; off < 16; off <<= 1)
                mx = fmaxf(mx, __shfl_xor(mx, off, 16));
            rmax[i] = mx;
            mnew[i] = fmaxf(m_i[i], mx);
            float s = 0.f;
#pragma unroll
            for (int jj = 0; jj < 4; ++jj) {
                const float p = __expf(sc[i][jj] - mnew[i]);
                sc[i][jj] = p;
                s += p;
            }
#pragma unroll
            for (int off = 1; off < 16; off <<= 1)
                s += __shfl_xor(s, off, 16);
            rsum[i] = s;
            scale[i] = __expf(m_i[i] - mnew[i]);   // 0 when m_i = -inf
            l_i[i] = l_i[i] * scale[i] + rsum[i];
            m_i[i] = mnew[i];
#pragma unroll
            for (int j = 0; j < 4; ++j) acc[i][j] *= scale[i];
        }

        // store P transposed: Ps[k_local][q_local]
#pragma unroll
        for (int i = 0; i < 4; ++i)
#pragma unroll
            for (int jj = 0; jj < 4; ++jj)
                Ps[tk + 16 * jj][tq * 4 + i] = sc[i][jj];
        __syncthreads();

        // ---- PV accumulate: acc[i][j] += sum_k P[k][q(i)] * V[k][d(tk*4+j)]
#pragma unroll 8
        for (int k = 0; k < 64; ++k) {
            float4 pv = *(const float4*)&Ps[k][tq * 4];
            float4 vv = *(const float4*)&Vs[k][tk * 4];
            const float p[4] = {pv.x, pv.y, pv.z, pv.w};
            const float vd[4] = {vv.x, vv.y, vv.z, vv.w};
#pragma unroll
            for (int i = 0; i < 4; ++i)
#pragma unroll
                for (int j = 0; j < 4; ++j)
                    acc[i][j] = fmaf(p[i], vd[j], acc[i][j]);
        }
    }

    // epilogue: ctx = acc / l, write to [B*S, H*Dh]
#pragma unroll
    for (int i = 0; i < 4; ++i) {
        const float inv = 1.0f / l_i[i];
        float4 v = make_float4(acc[i][0] * inv, acc[i][1] * inv,
                               acc[i][2] * inv, acc[i][3] * inv);
        *(float4*)&O[base + (size_t)(q0 + tq * 4 + i) * Dmod + tk * 4] = v;
    }
}

// ---------------------------------------------------------------------------
extern "C" void kernel_launch(void* const* d_in, const int* in_sizes, int n_in,
                              void* d_out, int out_size, void* d_ws, size_t ws_size,
                              hipStream_t stream) {
    const float* x  = (const float*)d_in[0];
    const float* Wq = (const float*)d_in[1];
    const float* Wk = (const float*)d_in[2];
    const float* Wv = (const float*)d_in[3];
    const float* Wo = (const float*)d_in[4];
    const float* bo = (const float*)d_in[5];
    float* out = (float*)d_out;
    float* ws  = (float*)d_ws;

    const size_t MN = (size_t)Mtot * Dmod;   // 8192*1024
    float* Qb = ws;
    float* Kb = ws + MN;
    float* Vb = ws + 2 * MN;
    float* Cb = ws + 3 * MN;

    dim3 gg(Dmod / 128, Mtot / 128);   // (8, 64)
    sgemm128<false><<<gg, 256, 0, stream>>>(x, Wq, nullptr, Qb, Mtot, Dmod, Dmod);
    sgemm128<false><<<gg, 256, 0, stream>>>(x, Wk, nullptr, Kb, Mtot, Dmod, Dmod);
    sgemm128<false><<<gg, 256, 0, stream>>>(x, Wv, nullptr, Vb, Mtot, Dmod, Dmod);

    attn_fused<<<dim3(SEQ / 64, 4 * NH), 256, 0, stream>>>(Qb, Kb, Vb, Cb);

    sgemm128<true><<<gg, 256, 0, stream>>>(Cb, Wo, bo, out, Mtot, Dmod, Dmod);
}

// Round 2
// 458.740 us; speedup vs baseline: 4.1529x; 4.1529x over previous
//
#include <hip/hip_runtime.h>
#include <hip/hip_bf16.h>
#include <math.h>

typedef __attribute__((ext_vector_type(8))) short bf16x8;   // 8 bf16 = 4 VGPR
typedef __attribute__((ext_vector_type(4))) float f32x4;

static constexpr int Mtot = 8192;   // B*S
static constexpr int Dmod = 1024;
static constexpr int SEQ  = 2048;
static constexpr int NH   = 16;
static constexpr int DH   = 64;

// fp32 -> bf16 RNE
__device__ __forceinline__ unsigned short f2bf(float x) {
    unsigned int u = __float_as_uint(x);
    u += 0x7fff + ((u >> 16) & 1);
    return (unsigned short)(u >> 16);
}

// async global->LDS, 16B per lane. LDS dest = wave-uniform base + lane*16.
__device__ __forceinline__ void gload_lds16(const void* g, void* l) {
    __builtin_amdgcn_global_load_lds(
        (const __attribute__((address_space(1))) unsigned int*)g,
        (__attribute__((address_space(3))) unsigned int*)l, 16, 0, 0);
}

// ---------------------------------------------------------------------------
// x fp32 -> bf16
// ---------------------------------------------------------------------------
__global__ __launch_bounds__(256)
void cvt_bf16(const float* __restrict__ in, unsigned short* __restrict__ out, int n4) {
    int i = blockIdx.x * blockDim.x + threadIdx.x;
    const int stride = gridDim.x * blockDim.x;
    for (; i < n4; i += stride) {
        float4 v = ((const float4*)in)[i];
        ushort4 o;
        o.x = f2bf(v.x); o.y = f2bf(v.y); o.z = f2bf(v.z); o.w = f2bf(v.w);
        ((ushort4*)out)[i] = o;
    }
}

// ---------------------------------------------------------------------------
// W[k][n] fp32 -> Wt[n][k] bf16 (transpose so GEMM B-fragments read contig K)
// ---------------------------------------------------------------------------
__global__ __launch_bounds__(256)
void transpose_cvt(const float* __restrict__ W, unsigned short* __restrict__ Wt) {
    __shared__ float tile[64][68];          // [n_local][k_local], padded
    const int n0 = blockIdx.x * 64, k0 = blockIdx.y * 64;
    const int t = threadIdx.x;
    const int r = t >> 4, c4 = (t & 15) * 4;
#pragma unroll
    for (int i = 0; i < 4; ++i) {
        float4 v = *(const float4*)&W[(size_t)(k0 + r + i * 16) * Dmod + n0 + c4];
        tile[c4 + 0][r + i * 16] = v.x;
        tile[c4 + 1][r + i * 16] = v.y;
        tile[c4 + 2][r + i * 16] = v.z;
        tile[c4 + 3][r + i * 16] = v.w;
    }
    __syncthreads();
#pragma unroll
    for (int i = 0; i < 4; ++i) {
        ushort4 o;
        o.x = f2bf(tile[r + i * 16][c4 + 0]);
        o.y = f2bf(tile[r + i * 16][c4 + 1]);
        o.z = f2bf(tile[r + i * 16][c4 + 2]);
        o.w = f2bf(tile[r + i * 16][c4 + 3]);
        *(ushort4*)&Wt[(size_t)(n0 + r + i * 16) * Dmod + k0 + c4] = o;
    }
}

// ---------------------------------------------------------------------------
// MFMA GEMM core: 128x128 tile, BK=32, 4 waves (2x2), 64x64 per wave.
// A[m][k] bf16, Wt[n][k] bf16. acc[mi][ni] = 16x16 fragments.
// m97 structure: global_load_lds w16 staging, linear LDS, 2 barriers/K-step.
// ---------------------------------------------------------------------------
__device__ __forceinline__ void gemm_core(const unsigned short* __restrict__ A,
                                          const unsigned short* __restrict__ Wt,
                                          int m0, int n0, int K,
                                          short* As, short* Bs, f32x4 acc[4][4]) {
    const int t   = threadIdx.x;
    const int wid = t >> 6, l = t & 63;
    const int wr  = wid >> 1, wc = wid & 1;
    const int r16 = l & 15, g = l >> 4;
    const int srow = t >> 2;            // staging row 0..63 (+c*64)
    const int scol = (t & 3) * 8;       // staging col in bf16 elems

    for (int k0 = 0; k0 < K; k0 += 32) {
        __syncthreads();                 // prev iter's ds_reads done
#pragma unroll
        for (int c = 0; c < 2; ++c) {
            gload_lds16(A  + (size_t)(m0 + c * 64 + srow) * K + k0 + scol,
                        (char*)As + c * 4096 + wid * 1024);
            gload_lds16(Wt + (size_t)(n0 + c * 64 + srow) * K + k0 + scol,
                        (char*)Bs + c * 4096 + wid * 1024);
        }
        __syncthreads();                 // staging visible (vmcnt drained)
        bf16x8 af[4], bv[4];
#pragma unroll
        for (int mi = 0; mi < 4; ++mi)
            af[mi] = *(const bf16x8*)&As[(wr * 64 + mi * 16 + r16) * 32 + g * 8];
#pragma unroll
        for (int ni = 0; ni < 4; ++ni)
            bv[ni] = *(const bf16x8*)&Bs[(wc * 64 + ni * 16 + r16) * 32 + g * 8];
#pragma unroll
        for (int mi = 0; mi < 4; ++mi)
#pragma unroll
            for (int ni = 0; ni < 4; ++ni)
                acc[mi][ni] = __builtin_amdgcn_mfma_f32_16x16x32_bf16(
                    af[mi], bv[ni], acc[mi][ni], 0, 0, 0);
    }
}

// ---------------------------------------------------------------------------
// Fused QKV projection. grid (24, 64): x = region*8 + ntile, y = mtile.
// Q,K -> [8192][1024] bf16 row-major. V -> Vt[bh][64 d][2048 s] bf16.
// ---------------------------------------------------------------------------
__global__ __launch_bounds__(256)
void qkv_gemm(const unsigned short* __restrict__ xb,
              const unsigned short* __restrict__ wtq,
              const unsigned short* __restrict__ wtk,
              const unsigned short* __restrict__ wtv,
              unsigned short* __restrict__ Qb,
              unsigned short* __restrict__ Kb,
              unsigned short* __restrict__ Vtb) {
    __shared__ __align__(16) short As[128 * 32];
    __shared__ __align__(16) short Bs[128 * 32];
    const int region = blockIdx.x >> 3;
    const int n0 = (blockIdx.x & 7) * 128;
    const int m0 = blockIdx.y * 128;
    const unsigned short* Wt = region == 0 ? wtq : (region == 1 ? wtk : wtv);

    f32x4 acc[4][4];
    const f32x4 z = {0.f, 0.f, 0.f, 0.f};
#pragma unroll
    for (int i = 0; i < 4; ++i)
#pragma unroll
        for (int j = 0; j < 4; ++j) acc[i][j] = z;

    gemm_core(xb, Wt, m0, n0, Dmod, As, Bs, acc);

    const int t = threadIdx.x, wid = t >> 6, l = t & 63;
    const int wr = wid >> 1, wc = wid & 1, r16 = l & 15, g = l >> 4;

    if (region <= 1) {
        unsigned short* out = region ? Kb : Qb;
#pragma unroll
        for (int mi = 0; mi < 4; ++mi) {
            const int mrow = m0 + wr * 64 + mi * 16 + g * 4;
#pragma unroll
            for (int ni = 0; ni < 4; ++ni) {
                const int ncol = n0 + wc * 64 + ni * 16 + r16;
#pragma unroll
                for (int reg = 0; reg < 4; ++reg)
                    out[(size_t)(mrow + reg) * Dmod + ncol] = f2bf(acc[mi][ni][reg]);
            }
        }
    } else {
#pragma unroll
        for (int mi = 0; mi < 4; ++mi) {
            const int mrow = m0 + wr * 64 + mi * 16 + g * 4;
            const int b = mrow >> 11, s = mrow & 2047;   // 4 regs = 4 consecutive s
#pragma unroll
            for (int ni = 0; ni < 4; ++ni) {
                const int n = n0 + wc * 64 + ni * 16 + r16;
                const int bh = b * NH + (n >> 6), d = n & 63;
                ushort4 o;
                o.x = f2bf(acc[mi][ni][0]); o.y = f2bf(acc[mi][ni][1]);
                o.z = f2bf(acc[mi][ni][2]); o.w = f2bf(acc[mi][ni][3]);
                *(ushort4*)&Vtb[((size_t)bh * DH + d) * SEQ + s] = o;
            }
        }
    }
}

// ---------------------------------------------------------------------------
// Output projection: out = Cx @ Wo + bo, fp32 out.
// ---------------------------------------------------------------------------
__global__ __launch_bounds__(256)
void out_gemm(const unsigned short* __restrict__ Cx,
              const unsigned short* __restrict__ wto,
              const float* __restrict__ bias,
              float* __restrict__ out) {
    __shared__ __align__(16) short As[128 * 32];
    __shared__ __align__(16) short Bs[128 * 32];
    const int n0 = blockIdx.x * 128, m0 = blockIdx.y * 128;

    f32x4 acc[4][4];
    const f32x4 z = {0.f, 0.f, 0.f, 0.f};
#pragma unroll
    for (int i = 0; i < 4; ++i)
#pragma unroll
        for (int j = 0; j < 4; ++j) acc[i][j] = z;

    gemm_core(Cx, wto, m0, n0, Dmod, As, Bs, acc);

    const int t = threadIdx.x, wid = t >> 6, l = t & 63;
    const int wr = wid >> 1, wc = wid & 1, r16 = l & 15, g = l >> 4;
    float bv[4];
#pragma unroll
    for (int ni = 0; ni < 4; ++ni) bv[ni] = bias[n0 + wc * 64 + ni * 16 + r16];
#pragma unroll
    for (int mi = 0; mi < 4; ++mi) {
        const int mrow = m0 + wr * 64 + mi * 16 + g * 4;
#pragma unroll
        for (int ni = 0; ni < 4; ++ni) {
            const int ncol = n0 + wc * 64 + ni * 16 + r16;
#pragma unroll
            for (int reg = 0; reg < 4; ++reg)
                out[(size_t)(mrow + reg) * Dmod + ncol] = acc[mi][ni][reg] + bv[ni];
        }
    }
}

// ---------------------------------------------------------------------------
// MFMA flash attention. Block = 256 thr (4 waves), one (b,h), 128 q-rows
// (32 per wave). KV tiles of 64. All LDS tiles: 128B rows, XOR-swizzled
// byte^=((row&7)<<4); staging applies the same XOR to the GLOBAL source so
// the LDS dest stays linear (global_load_lds requirement).
// ---------------------------------------------------------------------------
__global__ __launch_bounds__(256)
void attn_mfma(const unsigned short* __restrict__ Qg,
               const unsigned short* __restrict__ Kg,
               const unsigned short* __restrict__ Vtg,
               unsigned short* __restrict__ Ctx) {
    __shared__ __align__(16) short Qs[128 * 64];   // 16 KB
    __shared__ __align__(16) short Ks[64 * 64];    //  8 KB
    __shared__ __align__(16) short Vs[64 * 64];    //  8 KB  (Vt: [d][kv])
    __shared__ __align__(16) short Ps[4][32 * 64]; // 16 KB  (per-wave P)

    const int qt = 15 - blockIdx.x;        // heavy blocks dispatch first
    const int bh = blockIdx.y;
    const int b = bh >> 4, h = bh & 15;
    const int t = threadIdx.x, wid = t >> 6, l = t & 63;
    const int r16 = l & 15, g = l >> 4;
    const int q0 = qt * 128;

    const int srow8 = t >> 3;              // staging: 8 lanes per 128B row
    const int scolb = (t & 7) * 16;

    // ---- stage Q (128 rows x 128B), swizzled source
#pragma unroll
    for (int c = 0; c < 4; ++c) {
        const int row = c * 32 + srow8;
        const size_t src = ((size_t)(b * SEQ + q0 + row) * Dmod + h * DH) * 2
                         + (scolb ^ ((row & 7) << 4));
        gload_lds16((const char*)Qg + src, (char*)Qs + c * 4096 + wid * 1024);
    }
    __syncthreads();

    // ---- hoist Q fragments (constant over kv loop)
    bf16x8 aq[2][2];
#pragma unroll
    for (int qf = 0; qf < 2; ++qf) {
        const int row = wid * 32 + qf * 16 + r16;
#pragma unroll
        for (int kc = 0; kc < 2; ++kc)
            aq[qf][kc] = *(const bf16x8*)((const char*)Qs
                + row * 128 + ((kc * 64 + g * 16) ^ ((row & 7) << 4)));
    }

    float m_run[2][4], l_run[2][4];
    f32x4 oacc[2][4];
    const f32x4 z = {0.f, 0.f, 0.f, 0.f};
#pragma unroll
    for (int qf = 0; qf < 2; ++qf)
#pragma unroll
        for (int i = 0; i < 4; ++i) {
            m_run[qf][i] = -1e30f; l_run[qf][i] = 0.f; oacc[qf][i] = z;
        }

    const int jmax = 2 * qt + 1;
    for (int jt = 0; jt <= jmax; ++jt) {
        const int k0 = jt * 64;
        __syncthreads();                   // prev tile's K/V reads done
#pragma unroll
        for (int c = 0; c < 2; ++c) {
            const int row = c * 32 + srow8;
            const int swz = scolb ^ ((row & 7) << 4);
            const size_t srcK = ((size_t)(b * SEQ + k0 + row) * Dmod + h * DH) * 2 + swz;
            gload_lds16((const char*)Kg + srcK, (char*)Ks + c * 4096 + wid * 1024);
            const size_t srcV = ((size_t)(bh * DH + row) * SEQ + k0) * 2 + swz;
            gload_lds16((const char*)Vtg + srcV, (char*)Vs + c * 4096 + wid * 1024);
        }
        __syncthreads();                   // staged (vmcnt drained by barrier)

        // ---- S = Q K^T (fragments: rows q, cols kv)
        f32x4 sacc[2][4];
#pragma unroll
        for (int qf = 0; qf < 2; ++qf)
#pragma unroll
            for (int kf = 0; kf < 4; ++kf) sacc[qf][kf] = z;

        bf16x8 bk[4][2];
#pragma unroll
        for (int kf = 0; kf < 4; ++kf) {
            const int row = kf * 16 + r16;
#pragma unroll
            for (int kc = 0; kc < 2; ++kc)
                bk[kf][kc] = *(const bf16x8*)((const char*)Ks
                    + row * 128 + ((kc * 64 + g * 16) ^ ((row & 7) << 4)));
        }
#pragma unroll
        for (int qf = 0; qf < 2; ++qf)
#pragma unroll
            for (int kf = 0; kf < 4; ++kf)
#pragma unroll
                for (int kc = 0; kc < 2; ++kc)
                    sacc[qf][kf] = __builtin_amdgcn_mfma_f32_16x16x32_bf16(
                        aq[qf][kc], bk[kf][kc], sacc[qf][kf], 0, 0, 0);

        // ---- online softmax (rows live across 16 lanes; shfl_xor reduce)
        const bool need_mask = (jt >= 2 * qt);
#pragma unroll
        for (int qf = 0; qf < 2; ++qf) {
#pragma unroll
            for (int reg = 0; reg < 4; ++reg) {
                const int qrow = q0 + wid * 32 + qf * 16 + g * 4 + reg;
                float s[4];
                float mx = -1e30f;
#pragma unroll
                for (int kf = 0; kf < 4; ++kf) {
                    float v = sacc[qf][kf][reg] * 0.125f;
                    if (need_mask && (k0 + kf * 16 + r16) > qrow) v = -1e30f;
                    s[kf] = v;
                    mx = fmaxf(mx, v);
                }
#pragma unroll
                for (int off = 1; off < 16; off <<= 1)
                    mx = fmaxf(mx, __shfl_xor(mx, off, 16));
                const float mnew = fmaxf(m_run[qf][reg], mx);
                float sum = 0.f;
#pragma unroll
                for (int kf = 0; kf < 4; ++kf) {
                    const float p = __expf(s[kf] - mnew);
                    s[kf] = p; sum += p;
                }
#pragma unroll
                for (int off = 1; off < 16; off <<= 1)
                    sum += __shfl_xor(sum, off, 16);
                const float scale = __expf(m_run[qf][reg] - mnew);
                l_run[qf][reg] = l_run[qf][reg] * scale + sum;
                m_run[qf][reg] = mnew;
#pragma unroll
                for (int df = 0; df < 4; ++df) oacc[qf][df][reg] *= scale;

                const int prow = qf * 16 + g * 4 + reg;   // 0..31
#pragma unroll
                for (int kf = 0; kf < 4; ++kf) {
                    const int byte = prow * 128
                        + (((kf * 16 + r16) * 2) ^ ((prow & 7) << 4));
                    *(short*)((char*)&Ps[wid][0] + byte) = (short)f2bf(s[kf]);
                }
            }
        }

        // ---- O += P V  (A = P from LDS, B = Vt from LDS)
#pragma unroll
        for (int kc = 0; kc < 2; ++kc) {
            bf16x8 pa[2], vb[4];
#pragma unroll
            for (int qf = 0; qf < 2; ++qf) {
                const int row = qf * 16 + r16;
                pa[qf] = *(const bf16x8*)((const char*)&Ps[wid][0]
                    + row * 128 + ((kc * 64 + g * 16) ^ ((row & 7) << 4)));
            }
#pragma unroll
            for (int df = 0; df < 4; ++df) {
                const int row = df * 16 + r16;
                vb[df] = *(const bf16x8*)((const char*)Vs
                    + row * 128 + ((kc * 64 + g * 16) ^ ((row & 7) << 4)));
            }
#pragma unroll
            for (int qf = 0; qf < 2; ++qf)
#pragma unroll
                for (int df = 0; df < 4; ++df)
                    oacc[qf][df] = __builtin_amdgcn_mfma_f32_16x16x32_bf16(
                        pa[qf], vb[df], oacc[qf][df], 0, 0, 0);
        }
    }

    // ---- epilogue: ctx = O / l  -> bf16 [8192][1024]
#pragma unroll
    for (int qf = 0; qf < 2; ++qf) {
#pragma unroll
        for (int reg = 0; reg < 4; ++reg) {
            const float inv = 1.0f / l_run[qf][reg];
            const int qrow = q0 + wid * 32 + qf * 16 + g * 4 + reg;
            const size_t rb = (size_t)(b * SEQ + qrow) * Dmod + h * DH + r16;
#pragma unroll
            for (int df = 0; df < 4; ++df)
                Ctx[rb + df * 16] = f2bf(oacc[qf][df][reg] * inv);
        }
    }
}

// ---------------------------------------------------------------------------
extern "C" void kernel_launch(void* const* d_in, const int* in_sizes, int n_in,
                              void* d_out, int out_size, void* d_ws, size_t ws_size,
                              hipStream_t stream) {
    const float* x  = (const float*)d_in[0];
    const float* Wq = (const float*)d_in[1];
    const float* Wk = (const float*)d_in[2];
    const float* Wv = (const float*)d_in[3];
    const float* Wo = (const float*)d_in[4];
    const float* bo = (const float*)d_in[5];
    float* out = (float*)d_out;

    const size_t MD = (size_t)Mtot * Dmod;   // 8.4M elems
    const size_t DD = (size_t)Dmod * Dmod;
    unsigned short* xb  = (unsigned short*)d_ws;
    unsigned short* wtq = xb  + MD;
    unsigned short* wtk = wtq + DD;
    unsigned short* wtv = wtk + DD;
    unsigned short* wto = wtv + DD;
    unsigned short* Qb  = wto + DD;
    unsigned short* Kb  = Qb  + MD;
    unsigned short* Vtb = Kb  + MD;
    unsigned short* Cx  = Vtb + MD;

    cvt_bf16<<<2048, 256, 0, stream>>>(x, xb, (int)(MD / 4));
    transpose_cvt<<<dim3(16, 16), 256, 0, stream>>>(Wq, wtq);
    transpose_cvt<<<dim3(16, 16), 256, 0, stream>>>(Wk, wtk);
    transpose_cvt<<<dim3(16, 16), 256, 0, stream>>>(Wv, wtv);
    transpose_cvt<<<dim3(16, 16), 256, 0, stream>>>(Wo, wto);

    qkv_gemm<<<dim3(24, 64), 256, 0, stream>>>(xb, wtq, wtk, wtv, Qb, Kb, Vtb);

    attn_mfma<<<dim3(16, 64), 256, 0, stream>>>(Qb, Kb, Vtb, Cx);

    out_gemm<<<dim3(8, 64), 256, 0, stream>>>(Cx, wto, bo, out);
}

// Round 3
// 223.044 us; speedup vs baseline: 8.5414x; 2.0567x over previous
//
#include <hip/hip_runtime.h>
#include <hip/hip_bf16.h>
#include <math.h>

typedef __attribute__((ext_vector_type(8))) short bf16x8;   // 8 bf16 = 4 VGPR
typedef __attribute__((ext_vector_type(4))) float f32x4;

static constexpr int Mtot = 8192;   // B*S
static constexpr int Dmod = 1024;
static constexpr int SEQ  = 2048;
static constexpr int NH   = 16;
static constexpr int DH   = 64;

// fp32 -> bf16 RNE
__device__ __forceinline__ unsigned short f2bf(float x) {
    unsigned int u = __float_as_uint(x);
    u += 0x7fff + ((u >> 16) & 1);
    return (unsigned short)(u >> 16);
}

// async global->LDS, 16B per lane. LDS dest = wave-uniform base + lane*16.
__device__ __forceinline__ void gload_lds16(const void* g, void* l) {
    __builtin_amdgcn_global_load_lds(
        (const __attribute__((address_space(1))) unsigned int*)g,
        (__attribute__((address_space(3))) unsigned int*)l, 16, 0, 0);
}

// ---------------------------------------------------------------------------
// x fp32 -> bf16
// ---------------------------------------------------------------------------
__global__ __launch_bounds__(256)
void cvt_bf16(const float* __restrict__ in, unsigned short* __restrict__ out, int n4) {
    int i = blockIdx.x * blockDim.x + threadIdx.x;
    const int stride = gridDim.x * blockDim.x;
    for (; i < n4; i += stride) {
        float4 v = ((const float4*)in)[i];
        ushort4 o;
        o.x = f2bf(v.x); o.y = f2bf(v.y); o.z = f2bf(v.z); o.w = f2bf(v.w);
        ((ushort4*)out)[i] = o;
    }
}

// ---------------------------------------------------------------------------
// W[k][n] fp32 -> Wt[n][k] bf16
// ---------------------------------------------------------------------------
__global__ __launch_bounds__(256)
void transpose_cvt(const float* __restrict__ W, unsigned short* __restrict__ Wt) {
    __shared__ float tile[64][68];
    const int n0 = blockIdx.x * 64, k0 = blockIdx.y * 64;
    const int t = threadIdx.x;
    const int r = t >> 4, c4 = (t & 15) * 4;
#pragma unroll
    for (int i = 0; i < 4; ++i) {
        float4 v = *(const float4*)&W[(size_t)(k0 + r + i * 16) * Dmod + n0 + c4];
        tile[c4 + 0][r + i * 16] = v.x;
        tile[c4 + 1][r + i * 16] = v.y;
        tile[c4 + 2][r + i * 16] = v.z;
        tile[c4 + 3][r + i * 16] = v.w;
    }
    __syncthreads();
#pragma unroll
    for (int i = 0; i < 4; ++i) {
        ushort4 o;
        o.x = f2bf(tile[r + i * 16][c4 + 0]);
        o.y = f2bf(tile[r + i * 16][c4 + 1]);
        o.z = f2bf(tile[r + i * 16][c4 + 2]);
        o.w = f2bf(tile[r + i * 16][c4 + 3]);
        *(ushort4*)&Wt[(size_t)(n0 + r + i * 16) * Dmod + k0 + c4] = o;
    }
}

// ---------------------------------------------------------------------------
// MFMA GEMM core: 128x128 tile, BK=32, 4 waves (2x2), 64x64 per wave.
// ---------------------------------------------------------------------------
__device__ __forceinline__ void gemm_core(const unsigned short* __restrict__ A,
                                          const unsigned short* __restrict__ Wt,
                                          int m0, int n0, int K,
                                          short* As, short* Bs, f32x4 acc[4][4]) {
    const int t   = threadIdx.x;
    const int wid = t >> 6, l = t & 63;
    const int wr  = wid >> 1, wc = wid & 1;
    const int r16 = l & 15, g = l >> 4;
    const int srow = t >> 2;
    const int scol = (t & 3) * 8;

    for (int k0 = 0; k0 < K; k0 += 32) {
        __syncthreads();
#pragma unroll
        for (int c = 0; c < 2; ++c) {
            gload_lds16(A  + (size_t)(m0 + c * 64 + srow) * K + k0 + scol,
                        (char*)As + c * 4096 + wid * 1024);
            gload_lds16(Wt + (size_t)(n0 + c * 64 + srow) * K + k0 + scol,
                        (char*)Bs + c * 4096 + wid * 1024);
        }
        __syncthreads();
        bf16x8 af[4], bv[4];
#pragma unroll
        for (int mi = 0; mi < 4; ++mi)
            af[mi] = *(const bf16x8*)&As[(wr * 64 + mi * 16 + r16) * 32 + g * 8];
#pragma unroll
        for (int ni = 0; ni < 4; ++ni)
            bv[ni] = *(const bf16x8*)&Bs[(wc * 64 + ni * 16 + r16) * 32 + g * 8];
#pragma unroll
        for (int mi = 0; mi < 4; ++mi)
#pragma unroll
            for (int ni = 0; ni < 4; ++ni)
                acc[mi][ni] = __builtin_amdgcn_mfma_f32_16x16x32_bf16(
                    af[mi], bv[ni], acc[mi][ni], 0, 0, 0);
    }
}

// ---------------------------------------------------------------------------
// Fused QKV projection. Q gets the 1/8 softmax scale folded in.
// ---------------------------------------------------------------------------
__global__ __launch_bounds__(256)
void qkv_gemm(const unsigned short* __restrict__ xb,
              const unsigned short* __restrict__ wtq,
              const unsigned short* __restrict__ wtk,
              const unsigned short* __restrict__ wtv,
              unsigned short* __restrict__ Qb,
              unsigned short* __restrict__ Kb,
              unsigned short* __restrict__ Vtb) {
    __shared__ __align__(16) short As[128 * 32];
    __shared__ __align__(16) short Bs[128 * 32];
    const int region = blockIdx.x >> 3;
    const int n0 = (blockIdx.x & 7) * 128;
    const int m0 = blockIdx.y * 128;
    const unsigned short* Wt = region == 0 ? wtq : (region == 1 ? wtk : wtv);

    f32x4 acc[4][4];
    const f32x4 z = {0.f, 0.f, 0.f, 0.f};
#pragma unroll
    for (int i = 0; i < 4; ++i)
#pragma unroll
        for (int j = 0; j < 4; ++j) acc[i][j] = z;

    gemm_core(xb, Wt, m0, n0, Dmod, As, Bs, acc);

    const int t = threadIdx.x, wid = t >> 6, l = t & 63;
    const int wr = wid >> 1, wc = wid & 1, r16 = l & 15, g = l >> 4;

    if (region <= 1) {
        unsigned short* out = region ? Kb : Qb;
        const float qs = region == 0 ? 0.125f : 1.0f;
#pragma unroll
        for (int mi = 0; mi < 4; ++mi) {
            const int mrow = m0 + wr * 64 + mi * 16 + g * 4;
#pragma unroll
            for (int ni = 0; ni < 4; ++ni) {
                const int ncol = n0 + wc * 64 + ni * 16 + r16;
#pragma unroll
                for (int reg = 0; reg < 4; ++reg)
                    out[(size_t)(mrow + reg) * Dmod + ncol] = f2bf(acc[mi][ni][reg] * qs);
            }
        }
    } else {
#pragma unroll
        for (int mi = 0; mi < 4; ++mi) {
            const int mrow = m0 + wr * 64 + mi * 16 + g * 4;
            const int b = mrow >> 11, s = mrow & 2047;
#pragma unroll
            for (int ni = 0; ni < 4; ++ni) {
                const int n = n0 + wc * 64 + ni * 16 + r16;
                const int bh = b * NH + (n >> 6), d = n & 63;
                ushort4 o;
                o.x = f2bf(acc[mi][ni][0]); o.y = f2bf(acc[mi][ni][1]);
                o.z = f2bf(acc[mi][ni][2]); o.w = f2bf(acc[mi][ni][3]);
                *(ushort4*)&Vtb[((size_t)bh * DH + d) * SEQ + s] = o;
            }
        }
    }
}

// ---------------------------------------------------------------------------
// Output projection
// ---------------------------------------------------------------------------
__global__ __launch_bounds__(256)
void out_gemm(const unsigned short* __restrict__ Cx,
              const unsigned short* __restrict__ wto,
              const float* __restrict__ bias,
              float* __restrict__ out) {
    __shared__ __align__(16) short As[128 * 32];
    __shared__ __align__(16) short Bs[128 * 32];
    const int n0 = blockIdx.x * 128, m0 = blockIdx.y * 128;

    f32x4 acc[4][4];
    const f32x4 z = {0.f, 0.f, 0.f, 0.f};
#pragma unroll
    for (int i = 0; i < 4; ++i)
#pragma unroll
        for (int j = 0; j < 4; ++j) acc[i][j] = z;

    gemm_core(Cx, wto, m0, n0, Dmod, As, Bs, acc);

    const int t = threadIdx.x, wid = t >> 6, l = t & 63;
    const int wr = wid >> 1, wc = wid & 1, r16 = l & 15, g = l >> 4;
    float bv[4];
#pragma unroll
    for (int ni = 0; ni < 4; ++ni) bv[ni] = bias[n0 + wc * 64 + ni * 16 + r16];
#pragma unroll
    for (int mi = 0; mi < 4; ++mi) {
        const int mrow = m0 + wr * 64 + mi * 16 + g * 4;
#pragma unroll
        for (int ni = 0; ni < 4; ++ni) {
            const int ncol = n0 + wc * 64 + ni * 16 + r16;
#pragma unroll
            for (int reg = 0; reg < 4; ++reg)
                out[(size_t)(mrow + reg) * Dmod + ncol] = acc[mi][ni][reg] + bv[ni];
        }
    }
}

// ---------------------------------------------------------------------------
// MFMA flash attention, v2.
//  * 512 blocks; block = (bh, pair p) doing q-tiles {15-p, p}: 34 kv-tiles each.
//  * XCD-aware id decode: all blocks of 8 heads share one XCD (K/V = 4MB = L2).
//  * Swapped QK^T: S^T = mfma(K, Q) -> lane holds 16 kv values for q = lane&15;
//    softmax reduce = in-reg + 2 shfl_xor. Scale/l broadcast to the O-row
//    domain (q = 4g+reg) via tiny per-wave LDS array.
//  * K/V double-buffered, prefetch-1 (issue stage for tile j+1 before compute j).
// ---------------------------------------------------------------------------
__global__ __launch_bounds__(256)
void attn_mfma(const unsigned short* __restrict__ Qg,
               const unsigned short* __restrict__ Kg,
               const unsigned short* __restrict__ Vtg,
               unsigned short* __restrict__ Ctx) {
    __shared__ __align__(16) short Qs[128 * 64];     // 16 KB
    __shared__ __align__(16) short Ks[2][64 * 64];   // 16 KB
    __shared__ __align__(16) short Vs[2][64 * 64];   // 16 KB (Vt: [d][kv])
    __shared__ __align__(16) short Ps[4][32 * 64];   // 16 KB (per-wave P)
    __shared__ __align__(16) float sm[4][32];        // per-wave scale/l bcast

    const int id   = blockIdx.x;                 // 0..511
    const int bh   = ((id >> 6) << 3) | (id & 7);  // id%8 = XCD = bh low bits
    const int pidx = (id >> 3) & 7;
    const int b = bh >> 4, h = bh & 15;
    const int t = threadIdx.x, wid = t >> 6, l = t & 63;
    const int r16 = l & 15, g = l >> 4;
    const int srow8 = t >> 3;                    // 0..31
    const int scolb = (t & 7) * 16;

    auto stageKV = [&](int jt, int buf) {
        const int k0s = jt * 64;
#pragma unroll
        for (int c = 0; c < 2; ++c) {
            const int row = c * 32 + srow8;
            const int swz = scolb ^ ((row & 7) << 4);
            const size_t srcK = ((size_t)(b * SEQ + k0s + row) * Dmod + h * DH) * 2 + swz;
            gload_lds16((const char*)Kg + srcK, (char*)&Ks[buf][0] + c * 4096 + wid * 1024);
            const size_t srcV = ((size_t)(bh * DH + row) * SEQ + k0s) * 2 + swz;
            gload_lds16((const char*)Vtg + srcV, (char*)&Vs[buf][0] + c * 4096 + wid * 1024);
        }
    };

    for (int pass = 0; pass < 2; ++pass) {
        const int qt = pass ? pidx : 15 - pidx;  // heavy tile first
        const int q0 = qt * 128;
        const int jmax = 2 * qt + 1;

        __syncthreads();                         // Qs/buf0 safe to rewrite
        // stage Q (128 rows x 128B), swizzled source
#pragma unroll
        for (int c = 0; c < 4; ++c) {
            const int row = c * 32 + srow8;
            const size_t src = ((size_t)(b * SEQ + q0 + row) * Dmod + h * DH) * 2
                             + (scolb ^ ((row & 7) << 4));
            gload_lds16((const char*)Qg + src, (char*)Qs + c * 4096 + wid * 1024);
        }
        stageKV(0, 0);
        __syncthreads();                         // Q + KV0 landed

        // hoist Q fragments (B-operand: col = q = lane&15, k = d)
        bf16x8 bq[2][2];
#pragma unroll
        for (int qf = 0; qf < 2; ++qf) {
            const int row = wid * 32 + qf * 16 + r16;
#pragma unroll
            for (int kc = 0; kc < 2; ++kc)
                bq[qf][kc] = *(const bf16x8*)((const char*)Qs
                    + row * 128 + ((kc * 64 + g * 16) ^ ((row & 7) << 4)));
        }

        float m_run[2] = {-1e30f, -1e30f};
        float l_run[2] = {0.f, 0.f};
        f32x4 oacc[2][4];
        const f32x4 z = {0.f, 0.f, 0.f, 0.f};
#pragma unroll
        for (int qf = 0; qf < 2; ++qf)
#pragma unroll
            for (int df = 0; df < 4; ++df) oacc[qf][df] = z;

        int cur = 0;
        for (int jt = 0; jt <= jmax; ++jt) {
            if (jt < jmax) stageKV(jt + 1, cur ^ 1);   // prefetch next tile

            // ---- S^T = K Q^T: A = K (rows kv), B = Q (cols q)
            bf16x8 ak[4][2];
#pragma unroll
            for (int kf = 0; kf < 4; ++kf) {
                const int row = kf * 16 + r16;
#pragma unroll
                for (int kc = 0; kc < 2; ++kc)
                    ak[kf][kc] = *(const bf16x8*)((const char*)&Ks[cur][0]
                        + row * 128 + ((kc * 64 + g * 16) ^ ((row & 7) << 4)));
            }
            f32x4 st[2][4];
#pragma unroll
            for (int qf = 0; qf < 2; ++qf)
#pragma unroll
                for (int kf = 0; kf < 4; ++kf) st[qf][kf] = z;
#pragma unroll
            for (int qf = 0; qf < 2; ++qf)
#pragma unroll
                for (int kf = 0; kf < 4; ++kf)
#pragma unroll
                    for (int kc = 0; kc < 2; ++kc)
                        st[qf][kf] = __builtin_amdgcn_mfma_f32_16x16x32_bf16(
                            ak[kf][kc], bq[qf][kc], st[qf][kf], 0, 0, 0);

            // ---- in-register online softmax (lane owns q = lane&15 row slice)
            const int k0 = jt * 64;
            const bool need_mask = (jt >= 2 * qt);
#pragma unroll
            for (int qf = 0; qf < 2; ++qf) {
                const int qg = q0 + wid * 32 + qf * 16 + r16;
                float p[16];
#pragma unroll
                for (int kf = 0; kf < 4; ++kf)
#pragma unroll
                    for (int r = 0; r < 4; ++r) {
                        float v = st[qf][kf][r];
                        if (need_mask && (k0 + kf * 16 + g * 4 + r) > qg) v = -1e30f;
                        p[kf * 4 + r] = v;
                    }
                float mx = p[0];
#pragma unroll
                for (int i = 1; i < 16; ++i) mx = fmaxf(mx, p[i]);
                mx = fmaxf(mx, __shfl_xor(mx, 16));
                mx = fmaxf(mx, __shfl_xor(mx, 32));
                const float mnew = fmaxf(m_run[qf], mx);
                float sum = 0.f;
#pragma unroll
                for (int i = 0; i < 16; ++i) { p[i] = __expf(p[i] - mnew); sum += p[i]; }
                sum += __shfl_xor(sum, 16);
                sum += __shfl_xor(sum, 32);
                const float scale = __expf(m_run[qf] - mnew);
                l_run[qf] = l_run[qf] * scale + sum;
                m_run[qf] = mnew;

                // pack P -> per-wave LDS, row = qf*16 + (lane&15), kv = 16kf+4g+r
                const int prow = qf * 16 + r16;
#pragma unroll
                for (int kf = 0; kf < 4; ++kf) {
                    uint2 w;
                    w.x = (unsigned int)f2bf(p[kf * 4 + 0])
                        | ((unsigned int)f2bf(p[kf * 4 + 1]) << 16);
                    w.y = (unsigned int)f2bf(p[kf * 4 + 2])
                        | ((unsigned int)f2bf(p[kf * 4 + 3]) << 16);
                    const int byte = prow * 128 + ((kf * 32 + g * 8) ^ ((prow & 7) << 4));
                    *(uint2*)((char*)&Ps[wid][0] + byte) = w;
                }
                if (g == 0) sm[wid][qf * 16 + r16] = scale;
            }

            // ---- rescale O (rows q = 4g+reg: fetch scale via wave-local bcast)
#pragma unroll
            for (int qf = 0; qf < 2; ++qf) {
                const f32x4 s4 = *(const f32x4*)&sm[wid][qf * 16 + 4 * g];
#pragma unroll
                for (int df = 0; df < 4; ++df) oacc[qf][df] *= s4;
            }

            // ---- O += P V  (A = P rows q, B = Vt cols d)
#pragma unroll
            for (int kc = 0; kc < 2; ++kc) {
                bf16x8 pa[2], vb[4];
#pragma unroll
                for (int qf = 0; qf < 2; ++qf) {
                    const int row = qf * 16 + r16;
                    pa[qf] = *(const bf16x8*)((const char*)&Ps[wid][0]
                        + row * 128 + ((kc * 64 + g * 16) ^ ((row & 7) << 4)));
                }
#pragma unroll
                for (int df = 0; df < 4; ++df) {
                    const int row = df * 16 + r16;
                    vb[df] = *(const bf16x8*)((const char*)&Vs[cur][0]
                        + row * 128 + ((kc * 64 + g * 16) ^ ((row & 7) << 4)));
                }
#pragma unroll
                for (int qf = 0; qf < 2; ++qf)
#pragma unroll
                    for (int df = 0; df < 4; ++df)
                        oacc[qf][df] = __builtin_amdgcn_mfma_f32_16x16x32_bf16(
                            pa[qf], vb[df], oacc[qf][df], 0, 0, 0);
            }

            __syncthreads();    // next buffer landed (vmcnt drained); reads done
            cur ^= 1;
        }

        // ---- epilogue: redistribute l to O-row domain, write ctx bf16
        if (g == 0) { sm[wid][r16] = l_run[0]; sm[wid][16 + r16] = l_run[1]; }
#pragma unroll
        for (int qf = 0; qf < 2; ++qf) {
            const f32x4 lv = *(const f32x4*)&sm[wid][qf * 16 + 4 * g];
#pragma unroll
            for (int reg = 0; reg < 4; ++reg) {
                const float inv = 1.0f / lv[reg];
                const int qrow = q0 + wid * 32 + qf * 16 + 4 * g + reg;
                const size_t rb = (size_t)(b * SEQ + qrow) * Dmod + h * DH + r16;
#pragma unroll
                for (int df = 0; df < 4; ++df)
                    Ctx[rb + df * 16] = f2bf(oacc[qf][df][reg] * inv);
            }
        }
    }
}

// ---------------------------------------------------------------------------
extern "C" void kernel_launch(void* const* d_in, const int* in_sizes, int n_in,
                              void* d_out, int out_size, void* d_ws, size_t ws_size,
                              hipStream_t stream) {
    const float* x  = (const float*)d_in[0];
    const float* Wq = (const float*)d_in[1];
    const float* Wk = (const float*)d_in[2];
    const float* Wv = (const float*)d_in[3];
    const float* Wo = (const float*)d_in[4];
    const float* bo = (const float*)d_in[5];
    float* out = (float*)d_out;

    const size_t MD = (size_t)Mtot * Dmod;
    const size_t DD = (size_t)Dmod * Dmod;
    unsigned short* xb  = (unsigned short*)d_ws;
    unsigned short* wtq = xb  + MD;
    unsigned short* wtk = wtq + DD;
    unsigned short* wtv = wtk + DD;
    unsigned short* wto = wtv + DD;
    unsigned short* Qb  = wto + DD;
    unsigned short* Kb  = Qb  + MD;
    unsigned short* Vtb = Kb  + MD;
    unsigned short* Cx  = Vtb + MD;

    cvt_bf16<<<2048, 256, 0, stream>>>(x, xb, (int)(MD / 4));
    transpose_cvt<<<dim3(16, 16), 256, 0, stream>>>(Wq, wtq);
    transpose_cvt<<<dim3(16, 16), 256, 0, stream>>>(Wk, wtk);
    transpose_cvt<<<dim3(16, 16), 256, 0, stream>>>(Wv, wtv);
    transpose_cvt<<<dim3(16, 16), 256, 0, stream>>>(Wo, wto);

    qkv_gemm<<<dim3(24, 64), 256, 0, stream>>>(xb, wtq, wtk, wtv, Qb, Kb, Vtb);

    attn_mfma<<<512, 256, 0, stream>>>(Qb, Kb, Vtb, Cx);

    out_gemm<<<dim3(8, 64), 256, 0, stream>>>(Cx, wto, bo, out);
}